// Round 6
// baseline (103.666 us; speedup 1.0000x reference)
//
#include <hip/hip_runtime.h>
#include <math.h>

// TripletHard B=8192 D=128 NC=256. Split design (r6):
//   prep : fp32->bf16 (RNE), K-major fbT, sq of rounded, class buckets.
//   pos  : per-class MFMA Gram (one wave/class) -> 2nd-smallest same-class d2.
//   main : neg-only (diff-class min) MFMA scan, 4 ops/element epilogue,
//          ~155 VGPR -> 3 waves/SIMD, barrier-free, LDS-free (fbT L2-resident).
//   merge: combine 32 n1 slices + pos_d2 -> mean hinge (device atomics).
// fbT8[kc*8192 + row] = features[row][kc*8..kc*8+7], kc=0..15.

#define BN 8192
#define MARGIN_F 1.0f
#define EPS_F 1e-5f
#define CLS_CAP 256

typedef __attribute__((ext_vector_type(8))) short short8;
typedef __attribute__((ext_vector_type(4))) float floatx4;

__device__ __forceinline__ unsigned short bf16_rne(float x, float& r) {
    unsigned u = __float_as_uint(x);
    u += 0x7FFF + ((u >> 16) & 1);
    unsigned short h = (unsigned short)(u >> 16);
    r = __uint_as_float(((unsigned)h) << 16);
    return h;
}

// 4 threads/row: bf16 convert, K-major write, sq from ROUNDED values,
// class bucketing (atomic), zero g_acc/counter.
__global__ __launch_bounds__(256) void prep_kernel(const float* __restrict__ f,
                                                   const int* __restrict__ lbl,
                                                   short8* __restrict__ fbT,
                                                   float* __restrict__ sq,
                                                   int* __restrict__ cls_cnt,
                                                   int* __restrict__ cls_idx,
                                                   float* __restrict__ g_acc,
                                                   unsigned* __restrict__ counter) {
    int gid = blockIdx.x * 256 + threadIdx.x;  // 0..32767
    if (gid == 0) { *g_acc = 0.f; *counter = 0u; }
    int row = gid >> 2, part = gid & 3;
    const float4* f4 = (const float4*)f + (size_t)row * 32 + part * 8;
    float s = 0.f;
#pragma unroll
    for (int cc = 0; cc < 4; ++cc) {  // chunk kc = part*4 + cc
        float4 v0 = f4[cc * 2], v1 = f4[cc * 2 + 1];
        float r0, r1, r2, r3, r4, r5, r6, r7;
        short8 o;
        o[0] = (short)bf16_rne(v0.x, r0);
        o[1] = (short)bf16_rne(v0.y, r1);
        o[2] = (short)bf16_rne(v0.z, r2);
        o[3] = (short)bf16_rne(v0.w, r3);
        o[4] = (short)bf16_rne(v1.x, r4);
        o[5] = (short)bf16_rne(v1.y, r5);
        o[6] = (short)bf16_rne(v1.z, r6);
        o[7] = (short)bf16_rne(v1.w, r7);
        fbT[(size_t)(part * 4 + cc) * BN + row] = o;
        s += r0 * r0 + r1 * r1 + r2 * r2 + r3 * r3 +
             r4 * r4 + r5 * r5 + r6 * r6 + r7 * r7;
    }
    s += __shfl_xor(s, 1, 4);
    s += __shfl_xor(s, 2, 4);
    if (part == 0) {
        sq[row] = s;
        int l = lbl[row];
        int idx = atomicAdd(&cls_cnt[l], 1);
        if (idx < CLS_CAP) cls_idx[l * CLS_CAP + idx] = row;
    }
}

// One wave per class: gathered MFMA Gram over the class members (64-tiles,
// pad columns masked to INF), 2nd-smallest d2 per member -> pos_d2[row].
__global__ __launch_bounds__(64) void pos_kernel(const short8* __restrict__ fbT,
                                                 const int* __restrict__ cls_cnt,
                                                 const int* __restrict__ cls_idx,
                                                 const float* __restrict__ sq,
                                                 float* __restrict__ pos_d2) {
    __shared__ int midx[CLS_CAP];
    const int cls = blockIdx.x;
    int n = cls_cnt[cls];
    if (n <= 0) return;
    if (n > CLS_CAP) n = CLS_CAP;
    const int lane = threadIdx.x;
    const int q = lane >> 4, c = lane & 15;

    for (int s = lane; s < CLS_CAP; s += 64) {
        int slot = (s < n) ? s : 0;
        midx[s] = cls_idx[cls * CLS_CAP + slot];
    }
    __syncthreads();

    const int nt = (n + 63) >> 6;
    for (int it = 0; it < nt; ++it) {
        short8 a[4][4];
#pragma unroll
        for (int mf = 0; mf < 4; ++mf) {
            int row = midx[it * 64 + mf * 16 + c];
#pragma unroll
            for (int ks = 0; ks < 4; ++ks)
                a[mf][ks] = fbT[(size_t)(ks * 4 + q) * BN + row];
        }
        float s1[4][4], s2[4][4];
#pragma unroll
        for (int mf = 0; mf < 4; ++mf)
#pragma unroll
            for (int rg = 0; rg < 4; ++rg) { s1[mf][rg] = INFINITY; s2[mf][rg] = INFINITY; }

        for (int jt = 0; jt < nt; ++jt) {
            short8 b[4][4];
            float sjv[4];
#pragma unroll
            for (int nf = 0; nf < 4; ++nf) {
                int jrow = midx[jt * 64 + nf * 16 + c];
#pragma unroll
                for (int ks = 0; ks < 4; ++ks)
                    b[ks][nf] = fbT[(size_t)(ks * 4 + q) * BN + jrow];
                sjv[nf] = sq[jrow];
            }
            floatx4 acc[4][4];
#pragma unroll
            for (int mf = 0; mf < 4; ++mf)
#pragma unroll
                for (int nf = 0; nf < 4; ++nf) acc[mf][nf] = (floatx4)0.f;
#pragma unroll
            for (int ks = 0; ks < 4; ++ks)
#pragma unroll
                for (int mf = 0; mf < 4; ++mf)
#pragma unroll
                    for (int nf = 0; nf < 4; ++nf)
                        acc[mf][nf] = __builtin_amdgcn_mfma_f32_16x16x32_bf16(
                            a[mf][ks], b[ks][nf], acc[mf][nf], 0, 0, 0);
#pragma unroll
            for (int nf = 0; nf < 4; ++nf) {
                int jslot = jt * 64 + nf * 16 + c;
                bool valid = (jslot < n);
#pragma unroll
                for (int mf = 0; mf < 4; ++mf)
#pragma unroll
                    for (int rg = 0; rg < 4; ++rg) {
                        float v = fmaf(-2.0f, acc[mf][nf][rg], sjv[nf]);
                        float vs = valid ? v : INFINITY;
                        s2[mf][rg] = fminf(s2[mf][rg], fmaxf(s1[mf][rg], vs));
                        s1[mf][rg] = fminf(s1[mf][rg], vs);
                    }
            }
        }
        // merge two-smallest across the 16 c-lanes
#pragma unroll
        for (int m = 1; m < 16; m <<= 1) {
#pragma unroll
            for (int mf = 0; mf < 4; ++mf)
#pragma unroll
                for (int rg = 0; rg < 4; ++rg) {
                    float o1 = __shfl_xor(s1[mf][rg], m, 16);
                    float o2 = __shfl_xor(s2[mf][rg], m, 16);
                    float lo = fminf(s1[mf][rg], o1);
                    float hi = fminf(fmaxf(s1[mf][rg], o1), fminf(s2[mf][rg], o2));
                    s1[mf][rg] = lo; s2[mf][rg] = hi;
                }
        }
        if (c == 0) {
#pragma unroll
            for (int mf = 0; mf < 4; ++mf)
#pragma unroll
                for (int rg = 0; rg < 4; ++rg) {
                    int slot = it * 64 + mf * 16 + q * 4 + rg;
                    if (slot < n) {
                        int row = midx[slot];
                        pos_d2[row] = sq[row] + s2[mf][rg];
                    }
                }
        }
    }
}

// Block: 256 thr = 4 waves, each wave an independent 64-row i-strip.
// Wave tile 64x64, A-frags resident; per-nf step: b[4] transient + acc[4].
// neg-only epilogue: 4 VALU/element. Grid (32 i-blocks, 32 j-splits of 4
// tiles) = 1024 blocks; lb(256,3) -> 3 waves/SIMD, 4th block queued.
__global__ __launch_bounds__(256, 3) void main_kernel(const short8* __restrict__ fbT,
                                                      const int* __restrict__ lbl,
                                                      const float* __restrict__ sq,
                                                      float* __restrict__ part) {
    const int t = threadIdx.x;
    const int lane = t & 63;
    const int wv = t >> 6;
    const int q = lane >> 4, c = lane & 15;
    const int i0 = blockIdx.x * 256 + wv * 64;
    const int g = blockIdx.y;  // j-split: tiles [g*4, g*4+4)

    short8 a[4][4];
#pragma unroll
    for (int mf = 0; mf < 4; ++mf) {
        int row = i0 + mf * 16 + c;
#pragma unroll
        for (int ks = 0; ks < 4; ++ks)
            a[mf][ks] = fbT[(size_t)(ks * 4 + q) * BN + row];
    }
    int li[4][4];
#pragma unroll
    for (int mf = 0; mf < 4; ++mf)
#pragma unroll
        for (int rg = 0; rg < 4; ++rg)
            li[mf][rg] = lbl[i0 + mf * 16 + q * 4 + rg];

    float n1[4][4];
#pragma unroll
    for (int mf = 0; mf < 4; ++mf)
#pragma unroll
        for (int rg = 0; rg < 4; ++rg) n1[mf][rg] = INFINITY;

#pragma unroll
    for (int jt = 0; jt < 4; ++jt) {
        const int j0 = g * 256 + jt * 64;
#pragma unroll
        for (int nf = 0; nf < 4; ++nf) {
            const int jc = j0 + nf * 16 + c;
            short8 b0 = fbT[(size_t)(0 * 4 + q) * BN + jc];
            short8 b1 = fbT[(size_t)(1 * 4 + q) * BN + jc];
            short8 b2 = fbT[(size_t)(2 * 4 + q) * BN + jc];
            short8 b3 = fbT[(size_t)(3 * 4 + q) * BN + jc];
            int lj = lbl[jc];
            float sj = sq[jc];

            floatx4 acc[4];
#pragma unroll
            for (int mf = 0; mf < 4; ++mf) acc[mf] = (floatx4)0.f;
#pragma unroll
            for (int mf = 0; mf < 4; ++mf)
                acc[mf] = __builtin_amdgcn_mfma_f32_16x16x32_bf16(a[mf][0], b0, acc[mf], 0, 0, 0);
#pragma unroll
            for (int mf = 0; mf < 4; ++mf)
                acc[mf] = __builtin_amdgcn_mfma_f32_16x16x32_bf16(a[mf][1], b1, acc[mf], 0, 0, 0);
#pragma unroll
            for (int mf = 0; mf < 4; ++mf)
                acc[mf] = __builtin_amdgcn_mfma_f32_16x16x32_bf16(a[mf][2], b2, acc[mf], 0, 0, 0);
#pragma unroll
            for (int mf = 0; mf < 4; ++mf)
                acc[mf] = __builtin_amdgcn_mfma_f32_16x16x32_bf16(a[mf][3], b3, acc[mf], 0, 0, 0);

#pragma unroll
            for (int mf = 0; mf < 4; ++mf)
#pragma unroll
                for (int rg = 0; rg < 4; ++rg) {
                    float v = fmaf(-2.0f, acc[mf][rg], sj);
                    float vd = (li[mf][rg] == lj) ? INFINITY : v;
                    n1[mf][rg] = fminf(n1[mf][rg], vd);
                }
        }
    }

    // min across the 16 c-lanes sharing each accumulator row
#pragma unroll
    for (int m = 1; m < 16; m <<= 1) {
#pragma unroll
        for (int mf = 0; mf < 4; ++mf)
#pragma unroll
            for (int rg = 0; rg < 4; ++rg)
                n1[mf][rg] = fminf(n1[mf][rg], __shfl_xor(n1[mf][rg], m, 16));
    }
    if (c == 0) {
#pragma unroll
        for (int mf = 0; mf < 4; ++mf)
#pragma unroll
            for (int rg = 0; rg < 4; ++rg)
                part[g * BN + i0 + mf * 16 + q * 4 + rg] = n1[mf][rg];
    }
}

// combine 32 n1 slices + pos_d2 -> hinge; atomic sum; last block writes mean
__global__ __launch_bounds__(128) void merge_kernel(const float* __restrict__ part,
                                                    const float* __restrict__ sq,
                                                    const float* __restrict__ pos_d2,
                                                    float* __restrict__ g_acc,
                                                    unsigned* __restrict__ counter,
                                                    float* __restrict__ out) {
    int r = blockIdx.x * 128 + threadIdx.x;
    float n = INFINITY;
#pragma unroll
    for (int k = 0; k < 32; ++k) n = fminf(n, part[k * BN + r]);
    float si = sq[r];
    float pos = sqrtf(fmaxf(pos_d2[r] + EPS_F, 0.f));
    float neg = sqrtf(fmaxf(si + n + EPS_F, 0.f));
    float h = fmaxf(MARGIN_F + pos - neg, 0.f);
    __shared__ float red[2];
#pragma unroll
    for (int m = 32; m >= 1; m >>= 1) h += __shfl_down(h, m, 64);
    if ((threadIdx.x & 63) == 0) red[threadIdx.x >> 6] = h;
    __syncthreads();
    if (threadIdx.x == 0) {
        atomicAdd(g_acc, red[0] + red[1]);
        __threadfence();
        unsigned old = atomicAdd(counter, 1u);
        if (old == 63u) {
            float tot = atomicAdd(g_acc, 0.0f);
            out[0] = tot / (float)BN;
        }
    }
}

extern "C" void kernel_launch(void* const* d_in, const int* in_sizes, int n_in,
                              void* d_out, int out_size, void* d_ws, size_t ws_size,
                              hipStream_t stream) {
    const float* f = (const float*)d_in[0];
    const int* lbl = (const int*)d_in[1];
    char* ws = (char*)d_ws;
    float* sq = (float*)ws;                                   // 32 KB
    short8* fbT = (short8*)(ws + 32768);                      // 2 MB
    float* part = (float*)(ws + 32768 + 2097152);             // 1 MB (32 slices)
    float* pos_d2 = (float*)(ws + 32768 + 2097152 + 1048576); // 32 KB
    float* g_acc = (float*)(ws + 32768 + 2097152 + 1048576 + 32768);
    unsigned* counter = (unsigned*)(g_acc + 1);
    int* cls_cnt = (int*)(ws + 32768 + 2097152 + 1048576 + 32768 + 128);   // 1 KB
    int* cls_idx = (int*)((char*)cls_cnt + 1024);                          // 256 KB
    float* out = (float*)d_out;

    hipMemsetAsync(cls_cnt, 0, 256 * sizeof(int), stream);
    prep_kernel<<<128, 256, 0, stream>>>(f, lbl, fbT, sq, cls_cnt, cls_idx, g_acc, counter);
    pos_kernel<<<256, 64, 0, stream>>>(fbT, cls_cnt, cls_idx, sq, pos_d2);
    main_kernel<<<dim3(32, 32), 256, 0, stream>>>(fbT, lbl, sq, part);
    merge_kernel<<<64, 128, 0, stream>>>(part, sq, pos_d2, g_acc, counter, out);
}